// Round 5
// baseline (262.144 us; speedup 1.0000x reference)
//
#include <hip/hip_runtime.h>
#include <math.h>

#define D_MELS  80
#define T_DIM   4000
#define F4_ROW  20
#define NQ      10
#define NTHR    256
#define MAXB    1024
#define CHUNK   64      // rows per wave: 4 iterations x 16 rows

// quantities: 0=l1 1=band 2=diff2 3=tgt2 4=energy 5=mask 6=delta 7=dmask 8=delta2 9=d2mask

__global__ __launch_bounds__(NTHR) void mel_loss_main(
    const float* __restrict__ pred, const float* __restrict__ tgt,
    const float* __restrict__ mask, const float* __restrict__ w,
    float* __restrict__ partial, int BT, int total_waves)
{
    const int tid  = threadIdx.x;
    const int lane = tid & 63;
    const int qtr  = lane & 3;        // quarter of row: float4s qtr+4k, k=0..4
    const int rw   = lane >> 2;       // row within 16-row stripe
    const int gwave = blockIdx.x * (NTHR / 64) + (tid >> 6);

    const float4* p4 = (const float4*)pred;
    const float4* q4 = (const float4*)tgt;

    float4 wv[5];
    #pragma unroll
    for (int k = 0; k < 5; ++k) wv[k] = ((const float4*)w)[qtr + 4 * k];

    float v_l1 = 0.f, v_band = 0.f, v_diff2 = 0.f, v_tgt2 = 0.f, v_energy = 0.f;
    float v_m = 0.f, v_d = 0.f, v_dm = 0.f, v_d2 = 0.f, v_d2m = 0.f;

    for (int wbase = gwave * CHUNK; wbase < BT; wbase += total_waves * CHUNK) {
        #pragma unroll
        for (int it = 0; it < CHUNK / 16; ++it) {
            int r = wbase + it * 16 + rw;
            bool active = (r < BT);
            int rc = active ? r : (BT - 1);
            int t = rc % T_DIM;
            bool has1 = (t >= 1);
            bool has2 = (t >= 2);

            const float4* pr = p4 + (size_t)rc * F4_ROW + qtr;
            const float4* qr = q4 + (size_t)rc * F4_ROW + qtr;

            // primary loads (the ONLY all-lane global traffic)
            float4 P[5], Q[5];
            #pragma unroll
            for (int k = 0; k < 5; ++k) { P[k] = pr[4 * k]; Q[k] = qr[4 * k]; }

            // stripe-boundary halo: rows 0,1 can't shuffle from below
            float4 F[5], G[5];
            #pragma unroll
            for (int k = 0; k < 5; ++k) {
                F[k] = make_float4(0.f, 0.f, 0.f, 0.f);
                G[k] = make_float4(0.f, 0.f, 0.f, 0.f);
            }
            if (rw == 0 && has1 && active) {
                const float4* pa = pr - F4_ROW;
                const float4* qa = qr - F4_ROW;
                #pragma unroll
                for (int k = 0; k < 5; ++k) {
                    float4 a = pa[4 * k], b = qa[4 * k];
                    F[k] = make_float4(a.x - b.x, a.y - b.y, a.z - b.z, a.w - b.w);
                }
            }
            if (rw <= 1 && has2 && active) {
                const float4* pb = pr - 2 * F4_ROW;
                const float4* qb = qr - 2 * F4_ROW;
                #pragma unroll
                for (int k = 0; k < 5; ++k) {
                    float4 a = pb[4 * k], b = qb[4 * k];
                    G[k] = make_float4(a.x - b.x, a.y - b.y, a.z - b.z, a.w - b.w);
                }
            }

            float mt = active ? mask[rc] : 0.f;
            float m1s = __shfl_up(mt, 4, 64);
            float m2s = __shfl_up(mt, 8, 64);
            float m1 = has1 ? (rw >= 1 ? m1s : mask[rc - 1]) : 0.f;
            float m2 = has2 ? (rw >= 2 ? m2s : mask[rc - 2]) : 0.f;
            if (!active) { m1 = 0.f; m2 = 0.f; }

            float dmv  = mt * m1;
            float d2mv = dmv * m2;

            float l1r = 0.f, bandr = 0.f, sqr = 0.f, t2r = 0.f, er = 0.f;
            float dr = 0.f, d2r = 0.f;

            #pragma unroll
            for (int k = 0; k < 5; ++k) {
                float4 e = make_float4(P[k].x - Q[k].x, P[k].y - Q[k].y,
                                       P[k].z - Q[k].z, P[k].w - Q[k].w);
                // e of row r-1 / r-2 live in lanes 4 / 8 below (same quarter)
                float4 s1, s2;
                s1.x = __shfl_up(e.x, 4, 64); s1.y = __shfl_up(e.y, 4, 64);
                s1.z = __shfl_up(e.z, 4, 64); s1.w = __shfl_up(e.w, 4, 64);
                s2.x = __shfl_up(e.x, 8, 64); s2.y = __shfl_up(e.y, 8, 64);
                s2.z = __shfl_up(e.z, 8, 64); s2.w = __shfl_up(e.w, 8, 64);
                float4 f, g;
                f.x = (rw >= 1) ? s1.x : F[k].x; f.y = (rw >= 1) ? s1.y : F[k].y;
                f.z = (rw >= 1) ? s1.z : F[k].z; f.w = (rw >= 1) ? s1.w : F[k].w;
                g.x = (rw >= 2) ? s2.x : G[k].x; g.y = (rw >= 2) ? s2.y : G[k].y;
                g.z = (rw >= 2) ? s2.z : G[k].z; g.w = (rw >= 2) ? s2.w : G[k].w;

                float a0 = fabsf(e.x), a1 = fabsf(e.y), a2 = fabsf(e.z), a3 = fabsf(e.w);
                l1r   += a0 + a1 + a2 + a3;
                bandr += a0 * wv[k].x + a1 * wv[k].y + a2 * wv[k].z + a3 * wv[k].w;
                sqr   += e.x * e.x + e.y * e.y + e.z * e.z + e.w * e.w;
                t2r   += Q[k].x * Q[k].x + Q[k].y * Q[k].y
                       + Q[k].z * Q[k].z + Q[k].w * Q[k].w;
                er    += e.x + e.y + e.z + e.w;
                dr    += fabsf(e.x - f.x) + fabsf(e.y - f.y)
                       + fabsf(e.z - f.z) + fabsf(e.w - f.w);
                d2r   += fabsf(e.x - 2.f * f.x + g.x) + fabsf(e.y - 2.f * f.y + g.y)
                       + fabsf(e.z - 2.f * f.z + g.z) + fabsf(e.w - 2.f * f.w + g.w);
            }

            v_l1    += l1r * mt;
            v_band  += bandr * mt;
            v_diff2 += sqr * mt;
            v_tgt2  += t2r * mt;
            v_d     += dr * dmv;
            v_d2    += d2r * d2mv;

            er += __shfl_xor(er, 1, 64);
            er += __shfl_xor(er, 2, 64);
            if (qtr == 0) {
                v_energy += fabsf(er) * mt;
                v_m   += mt;
                v_dm  += dmv;
                v_d2m += d2mv;
            }
        }
    }

    // ---- block reduction: wave shuffle -> LDS -> per-block store (NO atomics) ----
    float vals[NQ] = {v_l1, v_band, v_diff2, v_tgt2, v_energy,
                      v_m, v_d, v_dm, v_d2, v_d2m};
    #pragma unroll
    for (int q = 0; q < NQ; ++q) {
        float v = vals[q];
        #pragma unroll
        for (int off = 32; off > 0; off >>= 1)
            v += __shfl_down(v, off, 64);
        vals[q] = v;
    }
    __shared__ float red[NTHR / 64][NQ];
    int wave = tid >> 6;
    if (lane == 0) {
        #pragma unroll
        for (int q = 0; q < NQ; ++q) red[wave][q] = vals[q];
    }
    __syncthreads();
    if (tid < NQ) {
        float s = 0.f;
        #pragma unroll
        for (int wv2 = 0; wv2 < NTHR / 64; ++wv2) s += red[wv2][tid];
        partial[tid * MAXB + blockIdx.x] = s;
    }
}

__global__ __launch_bounds__(640) void mel_loss_finalize(
    const float* __restrict__ partial, const float* __restrict__ w,
    float* __restrict__ out, int nblk)
{
    const int tid = threadIdx.x;
    const int wv  = tid >> 6;        // quantity index 0..9
    const int lane = tid & 63;
    __shared__ float fin[NQ];

    float s = 0.f;
    for (int i = lane; i < nblk; i += 64) s += partial[wv * MAXB + i];
    #pragma unroll
    for (int off = 32; off > 0; off >>= 1) s += __shfl_down(s, off, 64);
    if (lane == 0) fin[wv] = s;
    __syncthreads();

    if (tid == 0) {
        float l1s = fin[0], bands = fin[1], diff2 = fin[2], tgt2 = fin[3];
        float energys = fin[4], ms = fin[5], ds = fin[6], dms = fin[7];
        float d2s = fin[8], d2ms = fin[9];

        float wsum = 0.f;
        for (int d = 0; d < D_MELS; ++d) wsum += w[d];
        float wmean = wsum / (float)D_MELS;

        float n1  = fmaxf(ms   * (float)D_MELS, 1.f);
        float nd  = fmaxf(dms  * (float)D_MELS, 1.f);
        float nd2 = fmaxf(d2ms * (float)D_MELS, 1.f);

        float l1_loss     = l1s / n1;
        float delta_loss  = ds / nd;
        float delta2_loss = d2s / nd2;
        float sc_num = sqrtf(diff2 / n1);
        float sc_den = fmaxf(sqrtf(tgt2 / n1), 1e-8f);
        float sc_loss = sc_num / sc_den;
        float band_loss = (bands / n1) / wmean;
        float energy_loss = (energys / (float)D_MELS) / fmaxf(ms, 1.f);

        out[0] = 1.0f * l1_loss + 0.5f * delta_loss + 0.25f * delta2_loss
               + 0.5f * sc_loss + 1.0f * band_loss + 0.5f * energy_loss;
    }
}

extern "C" void kernel_launch(void* const* d_in, const int* in_sizes, int n_in,
                              void* d_out, int out_size, void* d_ws, size_t ws_size,
                              hipStream_t stream) {
    const float* pred = (const float*)d_in[0];
    const float* tgt  = (const float*)d_in[1];
    const float* mask = (const float*)d_in[2];
    const float* w    = (const float*)d_in[3];
    int BT = in_sizes[2];                 // B*T = 256000
    float* partial = (float*)d_ws;        // NQ * MAXB floats

    int rows_per_block = (NTHR / 64) * CHUNK;               // 256
    int blocks_needed = (BT + rows_per_block - 1) / rows_per_block;  // 1000
    int grid = blocks_needed < MAXB ? blocks_needed : MAXB;
    int total_waves = grid * (NTHR / 64);

    mel_loss_main<<<grid, NTHR, 0, stream>>>(pred, tgt, mask, w, partial, BT, total_waves);
    mel_loss_finalize<<<1, 640, 0, stream>>>(partial, w, (float*)d_out, grid);
}

// Round 7
// 204.132 us; speedup vs baseline: 1.2842x; 1.2842x over previous
//
#include <hip/hip_runtime.h>
#include <math.h>

#define D_MELS  80
#define T_DIM   4000
#define F4_ROW  20     // float4 per row
#define NQ      10
#define NTHR    256
#define WPB     (NTHR / 64)   // waves per block = 4
#define RPW     16            // rows per wave-iteration
#define LDSROWS (RPW + 2)     // 18: rows 0,1 = halo (base-2, base-1)
#define MAXB    2048

// compiler-level fence: DS pipe is in-order per wave; we only need to stop
// LLVM from reordering cross-lane LDS write->read (per-thread alias analysis
// says they don't alias). wave_barrier is free at runtime.
#define WAVE_FENCE() do { __asm__ volatile("" ::: "memory"); \
                          __builtin_amdgcn_wave_barrier();    \
                          __asm__ volatile("" ::: "memory"); } while (0)

// quantities: 0=l1 1=band 2=diff2 3=tgt2 4=energy 5=mask 6=delta 7=dmask 8=delta2 9=d2mask

__global__ __launch_bounds__(NTHR) void mel_loss_main(
    const float* __restrict__ pred, const float* __restrict__ tgt,
    const float* __restrict__ mask, const float* __restrict__ w,
    float* __restrict__ partial, int BT, int total_waves)
{
    const int tid  = threadIdx.x;
    const int lane = tid & 63;
    const int qtr  = lane & 3;       // quarter: float4s qtr+4k, k=0..4
    const int rw   = lane >> 2;      // row within stripe, 0..15
    const int wid  = tid >> 6;
    const int gwave = blockIdx.x * WPB + wid;

    const float4* p4 = (const float4*)pred;
    const float4* q4 = (const float4*)tgt;

    __shared__ float4 ebuf[WPB][LDSROWS * F4_ROW];   // 4 x 18 x 20 x 16B = 23040 B
    __shared__ float  red[WPB][NQ];
    float4* my = ebuf[wid];

    float4 wv[5];
    #pragma unroll
    for (int k = 0; k < 5; ++k) wv[k] = ((const float4*)w)[qtr + 4 * k];

    float v_l1 = 0.f, v_band = 0.f, v_diff2 = 0.f, v_tgt2 = 0.f, v_energy = 0.f;
    float v_m = 0.f, v_d = 0.f, v_dm = 0.f, v_d2 = 0.f, v_d2m = 0.f;

    const int stride_rows = total_waves * RPW;

    for (int base = gwave * RPW; base < BT; base += stride_rows) {
        int r = base + rw;
        bool active = (r < BT);
        int rc = active ? r : (BT - 1);
        int t = rc % T_DIM;

        const float4* pr = p4 + (size_t)rc * F4_ROW + qtr;
        const float4* qr = q4 + (size_t)rc * F4_ROW + qtr;

        // ---- phase A: primary load, pointwise terms, stash e in LDS ----
        float4 ecur[5];
        float l1r = 0.f, bandr = 0.f, sqr = 0.f, t2r = 0.f, er = 0.f;
        #pragma unroll
        for (int k = 0; k < 5; ++k) {
            float4 e = make_float4(0.f, 0.f, 0.f, 0.f);
            if (active) {
                float4 p = pr[4 * k];
                float4 q = qr[4 * k];
                e.x = p.x - q.x; e.y = p.y - q.y;
                e.z = p.z - q.z; e.w = p.w - q.w;
                float a0 = fabsf(e.x), a1 = fabsf(e.y),
                      a2 = fabsf(e.z), a3 = fabsf(e.w);
                l1r   += a0 + a1 + a2 + a3;
                bandr += a0 * wv[k].x + a1 * wv[k].y + a2 * wv[k].z + a3 * wv[k].w;
                sqr   += e.x * e.x + e.y * e.y + e.z * e.z + e.w * e.w;
                t2r   += q.x * q.x + q.y * q.y + q.z * q.z + q.w * q.w;
                er    += e.x + e.y + e.z + e.w;
            }
            ecur[k] = e;
            my[(rw + 2) * F4_ROW + qtr + 4 * k] = e;
        }

        // ---- phase B: halo rows (LDS rows 0,1 = global base-2, base-1) ----
        if (rw <= 1) {
            bool hvalid = active && (t >= 2);
            const float4* ph = pr - 2 * F4_ROW;
            const float4* qh = qr - 2 * F4_ROW;
            #pragma unroll
            for (int k = 0; k < 5; ++k) {
                float4 he = make_float4(0.f, 0.f, 0.f, 0.f);
                if (hvalid) {
                    float4 a = ph[4 * k];
                    float4 b = qh[4 * k];
                    he.x = a.x - b.x; he.y = a.y - b.y;
                    he.z = a.z - b.z; he.w = a.w - b.w;
                }
                my[rw * F4_ROW + qtr + 4 * k] = he;
            }
        }

        // writes (phases A,B) must be visible before cross-lane reads (phase C)
        WAVE_FENCE();

        // ---- phase C: temporal terms from LDS (wave-private, no block barrier) ----
        float mt = active ? mask[rc] : 0.f;
        float m1 = (active && t >= 1) ? mask[rc - 1] : 0.f;
        float m2 = (active && t >= 2) ? mask[rc - 2] : 0.f;
        float dmv  = mt * m1;
        float d2mv = dmv * m2;

        float dr = 0.f, d2r = 0.f;
        #pragma unroll
        for (int k = 0; k < 5; ++k) {
            float4 e = ecur[k];
            float4 f = my[(rw + 1) * F4_ROW + qtr + 4 * k];
            float4 g = my[rw * F4_ROW + qtr + 4 * k];
            dr  += fabsf(e.x - f.x) + fabsf(e.y - f.y)
                 + fabsf(e.z - f.z) + fabsf(e.w - f.w);
            d2r += fabsf(e.x - 2.f * f.x + g.x) + fabsf(e.y - 2.f * f.y + g.y)
                 + fabsf(e.z - 2.f * f.z + g.z) + fabsf(e.w - 2.f * f.w + g.w);
        }

        v_l1    += l1r * mt;
        v_band  += bandr * mt;
        v_diff2 += sqr * mt;
        v_tgt2  += t2r * mt;
        v_d     += dr * dmv;
        v_d2    += d2r * d2mv;

        er += __shfl_xor(er, 1, 64);
        er += __shfl_xor(er, 2, 64);
        if (qtr == 0) {
            v_energy += fabsf(er) * mt;
            v_m   += mt;
            v_dm  += dmv;
            v_d2m += d2mv;
        }

        // WAR: next iteration's phase A overwrites rows phase C just read
        WAVE_FENCE();
    }

    // ---- final reduction: wave shuffle -> LDS -> per-block store (no atomics) ----
    float vals[NQ] = {v_l1, v_band, v_diff2, v_tgt2, v_energy,
                      v_m, v_d, v_dm, v_d2, v_d2m};
    #pragma unroll
    for (int q = 0; q < NQ; ++q) {
        float v = vals[q];
        #pragma unroll
        for (int off = 32; off > 0; off >>= 1)
            v += __shfl_down(v, off, 64);
        vals[q] = v;
    }
    if (lane == 0) {
        #pragma unroll
        for (int q = 0; q < NQ; ++q) red[wid][q] = vals[q];
    }
    __syncthreads();
    if (tid < NQ) {
        float s = 0.f;
        #pragma unroll
        for (int wv2 = 0; wv2 < WPB; ++wv2) s += red[wv2][tid];
        partial[tid * MAXB + blockIdx.x] = s;
    }
}

__global__ __launch_bounds__(640) void mel_loss_finalize(
    const float* __restrict__ partial, const float* __restrict__ w,
    float* __restrict__ out, int nblk)
{
    const int tid = threadIdx.x;
    const int wv  = tid >> 6;        // quantity index 0..9
    const int lane = tid & 63;
    __shared__ float fin[NQ];

    float s = 0.f;
    for (int i = lane; i < nblk; i += 64) s += partial[wv * MAXB + i];
    #pragma unroll
    for (int off = 32; off > 0; off >>= 1) s += __shfl_down(s, off, 64);
    if (lane == 0) fin[wv] = s;
    __syncthreads();

    if (tid == 0) {
        float l1s = fin[0], bands = fin[1], diff2 = fin[2], tgt2 = fin[3];
        float energys = fin[4], ms = fin[5], ds = fin[6], dms = fin[7];
        float d2s = fin[8], d2ms = fin[9];

        float wsum = 0.f;
        for (int d = 0; d < D_MELS; ++d) wsum += w[d];
        float wmean = wsum / (float)D_MELS;

        float n1  = fmaxf(ms   * (float)D_MELS, 1.f);
        float nd  = fmaxf(dms  * (float)D_MELS, 1.f);
        float nd2 = fmaxf(d2ms * (float)D_MELS, 1.f);

        float l1_loss     = l1s / n1;
        float delta_loss  = ds / nd;
        float delta2_loss = d2s / nd2;
        float sc_num = sqrtf(diff2 / n1);
        float sc_den = fmaxf(sqrtf(tgt2 / n1), 1e-8f);
        float sc_loss = sc_num / sc_den;
        float band_loss = (bands / n1) / wmean;
        float energy_loss = (energys / (float)D_MELS) / fmaxf(ms, 1.f);

        out[0] = 1.0f * l1_loss + 0.5f * delta_loss + 0.25f * delta2_loss
               + 0.5f * sc_loss + 1.0f * band_loss + 0.5f * energy_loss;
    }
}

extern "C" void kernel_launch(void* const* d_in, const int* in_sizes, int n_in,
                              void* d_out, int out_size, void* d_ws, size_t ws_size,
                              hipStream_t stream) {
    const float* pred = (const float*)d_in[0];
    const float* tgt  = (const float*)d_in[1];
    const float* mask = (const float*)d_in[2];
    const float* w    = (const float*)d_in[3];
    int BT = in_sizes[2];                 // B*T = 256000
    float* partial = (float*)d_ws;        // NQ * MAXB floats = 80 KB

    int block_iters = (BT + WPB * RPW - 1) / (WPB * RPW);   // 4000
    int grid = (block_iters + 1) / 2;                       // 2000 -> 2 iters/wave
    if (grid > MAXB) grid = MAXB;
    if (grid < 1) grid = 1;
    int total_waves = grid * WPB;

    mel_loss_main<<<grid, NTHR, 0, stream>>>(pred, tgt, mask, w, partial, BT, total_waves);
    mel_loss_finalize<<<1, 640, 0, stream>>>(partial, w, (float*)d_out, grid);
}